// Round 1
// 176.423 us; speedup vs baseline: 1.0287x; 1.0287x over previous
//
#include <hip/hip_runtime.h>
#include <hip/hip_bf16.h>
#include <stdint.h>

typedef __attribute__((ext_vector_type(8))) short short8;
typedef __attribute__((ext_vector_type(4))) short short4v;
typedef __attribute__((ext_vector_type(4))) float f32x4;

#define B_ 2
#define S_ 2048
#define D_ 1024
#define H_ 16
#define DK_ 64
#define M_ (B_*S_)   // 4096

// workspace layout (in shorts):
//   [0 .. 12582912)          Q | K | VT, each M_*D_ bf16 (VT is [B,H,DK,S])
//   [12582912 .. 16777216)   Xb  bf16 (M_*D_)
//   [16777216 .. 19922944)   Wqb|Wkb|Wvb bf16 (D_*D_ each)
#define WS_QKV   0
#define WS_XB    12582912
#define WS_WB    16777216

// softmax-in-base-2: fold 1/sqrt(DK) * log2(e) into Q
#define QSCALE (0.125f * 1.44269504088896f)

// async global->LDS, 16B per lane; lds base wave-uniform, lane i -> base + i*16
#define GLL16(g, l) __builtin_amdgcn_global_load_lds( \
    (const __attribute__((address_space(1))) void*)(g), \
    (__attribute__((address_space(3))) void*)(l), 16, 0, 0)

#define WAIT_VM0 asm volatile("s_waitcnt vmcnt(0)" ::: "memory")
#define WAIT_VM4 asm volatile("s_waitcnt vmcnt(4)" ::: "memory")
#define WAIT_VM8 asm volatile("s_waitcnt vmcnt(8)" ::: "memory")
#define WAIT_LGKM0 asm volatile("s_waitcnt lgkmcnt(0)" ::: "memory")
#define BARRIER_RAW asm volatile("s_barrier" ::: "memory")

static __device__ __forceinline__ short f2bf(float f){
  union { float f; unsigned u; } x; x.f = f;
  unsigned r = x.u + 0x7fff + ((x.u >> 16) & 1);   // round-to-nearest-even
  return (short)(r >> 16);
}

// ---------------------------------------------------------------------------
// Kernel 0: downcast f32 inputs (X, Wq, Wk, Wv) to bf16 in workspace.
// ---------------------------------------------------------------------------
__global__ __launch_bounds__(256) void cvt_bf16(
    const float* __restrict__ X,  const float* __restrict__ Wq,
    const float* __restrict__ Wk, const float* __restrict__ Wv,
    short* __restrict__ ws)
{
  const int z = blockIdx.z;
  const float* src; short* dst; int n;
  if (z == 0)      { src = X;  dst = ws + WS_XB;               n = M_*D_; }
  else if (z == 1) { src = Wq; dst = ws + WS_WB;               n = D_*D_; }
  else if (z == 2) { src = Wk; dst = ws + WS_WB + D_*D_;       n = D_*D_; }
  else             { src = Wv; dst = ws + WS_WB + 2*(D_*D_);   n = D_*D_; }
  const int stride = gridDim.x * blockDim.x * 4;
  for (int i = (blockIdx.x * blockDim.x + threadIdx.x) * 4; i < n; i += stride) {
    float4 v = *(const float4*)(src + i);
    short4v o;
    o.x = f2bf(v.x); o.y = f2bf(v.y); o.z = f2bf(v.z); o.w = f2bf(v.w);
    *(short4v*)(dst + i) = o;
  }
}

// ---------------------------------------------------------------------------
// Kernel 1: QKV projection, 256x256 tile, BK=32, 8 waves (2Mx4N), 512 thr.
// T2+T3+T4+T5 stack (8-phase-style schedule):
//   - 4 LDS K-tile buffers (A[256][32]|B[256][32] bf16 each = 32KB; 128KB tot)
//   - 2 phases per K-tile; per phase: ds_read frags, issue 2 global_load_lds
//     for tile kt+3, s_barrier, lgkmcnt(0), setprio(1), 16 MFMA, setprio(0),
//     s_barrier. Counted vmcnt(8) once per K-tile (drain tail at kt=29/30).
//   - XOR swizzle both-sides: linear gll dest + pre-swizzled global source,
//     swizzled ds_read (slot ^= row&3) -> conflict-free main loop.
// z in {0,1}: C = X@W^T + b -> [B,H,S,DK] (Q scaled). z==2: V^T -> [B,H,DK,S]
// via LDS-transposed epilogue (acc orientation identical for all z).
// ---------------------------------------------------------------------------
__global__ __launch_bounds__(512, 2) void qkv_gemm(
    const short* __restrict__ ws_in,
    const float* __restrict__ bq, const float* __restrict__ bk,
    const float* __restrict__ bv, short* __restrict__ qkv)
{
  const int z = blockIdx.z;
  const short* X  = ws_in + WS_XB;
  const short* Wm = ws_in + WS_WB + (size_t)z * (D_*D_);
  short* out = qkv + (size_t)z * (M_*D_);

  // 128KB: buffer i at i*16384; A = [0,8192), B = [8192,16384) (shorts)
  __shared__ __align__(16) short lds[65536];

  const int t = threadIdx.x;            // 0..511
  const int w = t >> 6, lane = t & 63;
  const int quad = lane >> 4, l16 = lane & 15;
  const int wm = w >> 2, wn = w & 3;    // wave grid 2(M) x 4(N)
  const int m0 = blockIdx.y * 256, n0 = blockIdx.x * 256;

  // staging: thread t covers row rl = t>>2 (o=0) / 128+rl (o=1), phys slot t&3.
  // phys slot p at row r holds logical slot p ^ (r&3)  (XOR involution).
  const int rl = t >> 2;
  const int sl = (t & 3) ^ (rl & 3);
  const short* sA0 = X  + (size_t)(m0 + rl) * D_ + sl*8;
  const short* sA1 = sA0 + (size_t)128 * D_;
  const short* sB0 = Wm + (size_t)(n0 + rl) * D_ + sl*8;
  const short* sB1 = sB0 + (size_t)128 * D_;
  const int ldsw = w << 9;              // per-wave lds chunk (shorts): w*1024B

  const int swz = quad ^ (l16 & 3);     // read-side swizzle (row&3 == l16&3)

  f32x4 acc[8][4];
  #pragma unroll
  for (int i=0;i<8;i++)
    #pragma unroll
    for (int j=0;j<4;j++) acc[i][j] = (f32x4){0.f,0.f,0.f,0.f};

  // prologue: stage K-tiles 0,1,2 into buffers 0,1,2 (12 vmem ops)
  #pragma unroll
  for (int p=0;p<3;p++){
    GLL16(sA0 + p*32, lds + p*16384 + ldsw);
    GLL16(sA1 + p*32, lds + p*16384 + 4096 + ldsw);
    GLL16(sB0 + p*32, lds + p*16384 + 8192 + ldsw);
    GLL16(sB1 + p*32, lds + p*16384 + 12288 + ldsw);
  }
  WAIT_VM8;        // tile 0 (oldest 4 ops) complete
  BARRIER_RAW;

  for (int kt = 0; kt < 32; kt++) {
    const int bf = kt & 3;
    const short* bufA = lds + bf*16384;
    const short* bufB = bufA + 8192;
    const int tb = (kt + 3) & 3;
    const int ko2 = (kt + 3) * 32;
    const bool st = (kt + 3) < 32;

    short8 aF[4], bF[4];
    // ---------------- phase A: M-half 0 ----------------
    #pragma unroll
    for (int mf=0; mf<4; mf++)
      aF[mf] = *(const short8*)(bufA + (wm*128 + mf*16 + l16)*32 + swz*8);
    #pragma unroll
    for (int nf=0; nf<4; nf++)
      bF[nf] = *(const short8*)(bufB + (wn*64 + nf*16 + l16)*32 + swz*8);
    if (st) {
      GLL16(sA0 + ko2, lds + tb*16384 + ldsw);
      GLL16(sA1 + ko2, lds + tb*16384 + 4096 + ldsw);
    }
    BARRIER_RAW;
    WAIT_LGKM0;
    __builtin_amdgcn_s_setprio(1);
    #pragma unroll
    for (int mf=0; mf<4; mf++)
      #pragma unroll
      for (int nf=0; nf<4; nf++)
        acc[mf][nf] = __builtin_amdgcn_mfma_f32_16x16x32_bf16(aF[mf], bF[nf], acc[mf][nf], 0,0,0);
    __builtin_amdgcn_s_setprio(0);
    BARRIER_RAW;

    // ---------------- phase B: M-half 1 (B frags reused) ----------------
    #pragma unroll
    for (int mf=0; mf<4; mf++)
      aF[mf] = *(const short8*)(bufA + (wm*128 + 64 + mf*16 + l16)*32 + swz*8);
    if (st) {
      GLL16(sB0 + ko2, lds + tb*16384 + 8192 + ldsw);
      GLL16(sB1 + ko2, lds + tb*16384 + 12288 + ldsw);
    }
    BARRIER_RAW;
    WAIT_LGKM0;
    __builtin_amdgcn_s_setprio(1);
    #pragma unroll
    for (int mf=0; mf<4; mf++)
      #pragma unroll
      for (int nf=0; nf<4; nf++)
        acc[4+mf][nf] = __builtin_amdgcn_mfma_f32_16x16x32_bf16(aF[mf], bF[nf], acc[4+mf][nf], 0,0,0);
    __builtin_amdgcn_s_setprio(0);
    // counted drain: next iter needs tile kt+1 (its 4 ops are the oldest)
    if      (kt < 29)  { WAIT_VM8; }
    else if (kt == 29) { WAIT_VM4; }
    else if (kt == 30) { WAIT_VM0; }
    BARRIER_RAW;
  }

  __syncthreads();   // K-loop done; reuse LDS for epilogue transpose

  if (z != 2) {
    const float scale = (z==0) ? QSCALE : 1.0f;
    const float* bias = (z==0) ? bq : bk;
    float bv4[4];
    #pragma unroll
    for (int nf=0; nf<4; nf++) bv4[nf] = bias[n0 + wn*64 + nf*16 + l16];
    short* ep = lds;                    // [128][264] per pass
    #pragma unroll
    for (int p=0; p<2; p++){
      if (wm == p){
        #pragma unroll
        for (int mf=0; mf<8; mf++)
          #pragma unroll
          for (int nf=0; nf<4; nf++)
            #pragma unroll
            for (int i=0; i<4; i++)
              ep[(mf*16 + quad*4 + i)*264 + wn*64 + nf*16 + l16] =
                  f2bf((acc[mf][nf][i] + bv4[nf]) * scale);
      }
      __syncthreads();
      #pragma unroll
      for (int it=0; it<8; it++){
        const int cid = it*512 + t;
        const int row = cid >> 5, cc = cid & 31;
        short8 vv = *(const short8*)(ep + row*264 + cc*8);
        const int m = m0 + p*128 + row, bidx = m >> 11, s = m & 2047;
        const int n = n0 + cc*8, h = n >> 6, dd = n & 63;
        *(short8*)(out + (((size_t)(bidx*H_ + h))*S_ + s)*DK_ + dd) = vv;
      }
      __syncthreads();
    }
  } else {
    float bv4[4];
    #pragma unroll
    for (int nf=0; nf<4; nf++) bv4[nf] = bv[n0 + wn*64 + nf*16 + l16];
    short* ep = lds;                    // [256][136] per pass (n-major)
    #pragma unroll
    for (int p=0; p<2; p++){
      if (wm == p){
        #pragma unroll
        for (int mf=0; mf<8; mf++)
          #pragma unroll
          for (int nf=0; nf<4; nf++)
            #pragma unroll
            for (int i=0; i<4; i++)
              ep[(wn*64 + nf*16 + l16)*136 + mf*16 + quad*4 + i] =
                  f2bf(acc[mf][nf][i] + bv4[nf]);
      }
      __syncthreads();
      #pragma unroll
      for (int it=0; it<8; it++){
        const int cid = it*512 + t;
        const int row = cid >> 4, cc = cid & 15;   // row = n_local 0..255
        short8 vv = *(const short8*)(ep + row*136 + cc*8);
        const int n = n0 + row, h = n >> 6, dd = n & 63;
        const int m0p = m0 + p*128;
        const int bidx = m0p >> 11;
        const int s = (m0p & 2047) + cc*8;
        *(short8*)(out + (((size_t)(bidx*H_ + h))*DK_ + dd)*S_ + s) = vv;
      }
      __syncthreads();
    }
  }
}

// ---------------------------------------------------------------------------
// Kernel 2: flash-style causal attention per (bh, 128-query tile).
// (unchanged this round — no counters implicating it yet)
// ---------------------------------------------------------------------------
__global__ __launch_bounds__(256, 3) void attn(
    const short* __restrict__ qkv, float* __restrict__ out)
{
  const int bh = blockIdx.y;                    // b*16 + h, 0..31
  const int qt = (gridDim.x - 1) - blockIdx.x;  // longest blocks first
  const short* Q  = qkv + (size_t)bh * (S_*DK_);
  const short* K  = Q + (size_t)(M_*D_);
  const short* VT = qkv + (size_t)(2*M_*D_) + (size_t)bh * (DK_*S_);  // [d][s]

  __shared__ short Kbuf[2][4096];   // [64][64] swizzled,  16KB
  __shared__ short Vbuf[2][4096];   // [64(d)][64(key)],   16KB
  __shared__ short Ps[8192];        // [qrow 128][64 keys] swizzled, 16KB

  const int t = threadIdx.x;
  const int w = t >> 6, lane = t & 63;
  const int quad = lane >> 4, l16 = lane & 15;
  const int sw = l16 & 7;
  const int lr = lane >> 3, lc = lane & 7;
  const int csrc = lc ^ lr;

  // Q fragments (B-operand) straight to registers
  short8 bq[2][2];
  #pragma unroll
  for (int kc=0;kc<2;kc++)
    #pragma unroll
    for (int mt=0;mt<2;mt++)
      bq[kc][mt] = *(const short8*)(Q + (size_t)(qt*128 + w*32 + mt*16 + l16)*DK_
                                      + (kc*4 + quad)*8);

  const int nkt = 2*qt + 2;
  // prime: K/V tile 0 into buffer 0
  #pragma unroll
  for (int j=0;j<2;j++){
    const int rb = (j*4 + w)*8;
    GLL16(K  + (size_t)(rb + lr)*DK_ + csrc*8, &Kbuf[0][0] + rb*64);
    GLL16(VT + (size_t)(rb + lr)*S_  + csrc*8, &Vbuf[0][0] + rb*64);
  }

  f32x4 o[2][4];
  float lsum[2];
  #pragma unroll
  for (int mt=0;mt<2;mt++){
    #pragma unroll
    for (int nd=0;nd<4;nd++) o[mt][nd] = (f32x4){0.f,0.f,0.f,0.f};
    lsum[mt] = 0.f;
  }

  const int pw_half = (quad & 1) * 4;
  const int pw_ckb  = quad >> 1;
  int cur = 0;

  for (int kt = 0; kt < nkt; kt++){
    WAIT_VM0;        // buf[cur] (and Q reg loads at kt==0) complete
    BARRIER_RAW;
    const int nxt = cur ^ 1;
    if (kt + 1 < nkt) {
      const int kb2 = (kt+1)*64;
      short* Kn = &Kbuf[nxt][0];
      short* Vn = &Vbuf[nxt][0];
      #pragma unroll
      for (int j=0;j<2;j++){
        const int rb = (j*4 + w)*8;
        GLL16(K  + (size_t)(kb2 + rb + lr)*DK_ + csrc*8, Kn + rb*64);
        GLL16(VT + (size_t)(rb + lr)*S_ + kb2 + csrc*8,  Vn + rb*64);
      }
    }
    const short* Kc = &Kbuf[cur][0];
    const short* Vc = &Vbuf[cur][0];
    const int kb = kt*64;

    // S^T = K @ Q^T: C row = key = ntk*16+quad*4+i, col = qrow = w*32+mt*16+l16
    f32x4 sc[4][2];
    #pragma unroll
    for (int ntk=0;ntk<4;ntk++)
      #pragma unroll
      for (int mt=0;mt<2;mt++) sc[ntk][mt] = (f32x4){0.f,0.f,0.f,0.f};
    #pragma unroll
    for (int kc=0;kc<2;kc++){
      const int xch = (kc*4 + quad) ^ sw;
      short8 ak[4];
      #pragma unroll
      for (int ntk=0;ntk<4;ntk++)
        ak[ntk] = *(const short8*)(Kc + (ntk*16 + l16)*64 + xch*8);
      #pragma unroll
      for (int ntk=0;ntk<4;ntk++)
        #pragma unroll
        for (int mt=0;mt<2;mt++)
          sc[ntk][mt] = __builtin_amdgcn_mfma_f32_16x16x32_bf16(ak[ntk], bq[kc][mt], sc[ntk][mt], 0,0,0);
    }

    // causal mask
    const int q0w = qt*128 + w*32;
    if (kb + 63 > q0w) {
      #pragma unroll
      for (int ntk=0;ntk<4;ntk++)
        #pragma unroll
        for (int mt=0;mt<2;mt++){
          const int qg = q0w + mt*16 + l16;
          #pragma unroll
          for (int i=0;i<4;i++){
            const int kg = kb + ntk*16 + quad*4 + i;
            if (kg > qg) sc[ntk][mt][i] = -3.0e38f;
          }
        }
    }

    // p = exp2(score); v_perm pair-pack (truncating bf16) -> one b64 store
    #pragma unroll
    for (int mt=0;mt<2;mt++){
      const int r = w*32 + mt*16 + l16;
      #pragma unroll
      for (int ntk=0;ntk<4;ntk++){
        float p0 = __builtin_amdgcn_exp2f(sc[ntk][mt][0]);
        float p1 = __builtin_amdgcn_exp2f(sc[ntk][mt][1]);
        float p2 = __builtin_amdgcn_exp2f(sc[ntk][mt][2]);
        float p3 = __builtin_amdgcn_exp2f(sc[ntk][mt][3]);
        lsum[mt] += (p0+p1) + (p2+p3);
        unsigned lo = __builtin_amdgcn_perm(__float_as_uint(p1), __float_as_uint(p0), 0x07060302u);
        unsigned hi = __builtin_amdgcn_perm(__float_as_uint(p3), __float_as_uint(p2), 0x07060302u);
        const int slot = (ntk*2 + pw_ckb) ^ sw;
        *(uint2*)(Ps + r*64 + slot*8 + pw_half) = make_uint2(lo, hi);
      }
    }
    asm volatile("" ::: "memory");  // same-wave LDS RAW: keep reads below writes

    // PV: o += P @ V
    #pragma unroll
    for (int kc=0;kc<2;kc++){
      const int xch = (kc*4 + quad) ^ sw;
      short8 pa[2], vb[4];
      #pragma unroll
      for (int mt=0;mt<2;mt++)
        pa[mt] = *(const short8*)(Ps + (w*32 + mt*16 + l16)*64 + xch*8);
      #pragma unroll
      for (int nd=0;nd<4;nd++)
        vb[nd] = *(const short8*)(Vc + (nd*16 + l16)*64 + xch*8);
      #pragma unroll
      for (int mt=0;mt<2;mt++)
        #pragma unroll
        for (int nd=0;nd<4;nd++)
          o[mt][nd] = __builtin_amdgcn_mfma_f32_16x16x32_bf16(pa[mt], vb[nd], o[mt][nd], 0,0,0);
    }
    cur = nxt;
  }

  // epilogue: reduce row sums over quads, redistribute, scale, store f32
  const int bb = bh >> 4, h = bh & 15;
  float linv[2];
  #pragma unroll
  for (int mt=0;mt<2;mt++){
    float rs = lsum[mt];
    rs += __shfl_xor(rs, 16, 64);
    rs += __shfl_xor(rs, 32, 64);
    linv[mt] = 1.0f / rs;
  }
  #pragma unroll
  for (int mt=0;mt<2;mt++){
    #pragma unroll
    for (int i=0;i<4;i++){
      const float lw = __shfl(linv[mt], (quad<<4) + (quad<<2) + i, 64);
      const int q = qt*128 + w*32 + mt*16 + quad*4 + i;
      #pragma unroll
      for (int nd=0;nd<4;nd++){
        const int d = nd*16 + l16;
        out[ ((size_t)bb*S_ + q)*D_ + h*DK_ + d ] = o[mt][nd][i] * lw;
      }
    }
  }
}

extern "C" void kernel_launch(void* const* d_in, const int* in_sizes, int n_in,
                              void* d_out, int out_size, void* d_ws, size_t ws_size,
                              hipStream_t stream)
{
  (void)in_sizes; (void)n_in; (void)out_size; (void)ws_size;
  const float* X  = (const float*)d_in[0];
  const float* Wq = (const float*)d_in[1];
  const float* bq = (const float*)d_in[2];
  const float* Wk = (const float*)d_in[3];
  const float* bk = (const float*)d_in[4];
  const float* Wv = (const float*)d_in[5];
  const float* bv = (const float*)d_in[6];
  short* ws  = (short*)d_ws;
  float* out = (float*)d_out;

  dim3 g0(1024, 1, 4);
  cvt_bf16<<<g0, dim3(256,1,1), 0, stream>>>(X, Wq, Wk, Wv, ws);
  dim3 g1(D_/256, M_/256, 3);       // 4 x 16 x 3 = 192 blocks, 512 thr
  qkv_gemm<<<g1, dim3(512,1,1), 0, stream>>>(ws, bq, bk, bv, ws + WS_QKV);
  dim3 g2(S_/128, B_*H_);           // 16 x 32
  attn<<<g2, dim3(256,1,1), 0, stream>>>(ws + WS_QKV, out);
}

// Round 2
// 175.220 us; speedup vs baseline: 1.0358x; 1.0069x over previous
//
#include <hip/hip_runtime.h>
#include <hip/hip_bf16.h>
#include <stdint.h>

typedef __attribute__((ext_vector_type(8))) short short8;
typedef __attribute__((ext_vector_type(4))) short short4v;
typedef __attribute__((ext_vector_type(4))) float f32x4;
typedef __attribute__((ext_vector_type(16))) float f32x16;

#define B_ 2
#define S_ 2048
#define D_ 1024
#define H_ 16
#define DK_ 64
#define M_ (B_*S_)   // 4096

// workspace layout (in shorts):
//   [0 .. 12582912)          Q | K | VT, each M_*D_ bf16 (VT is [B,H,DK,S])
//   [12582912 .. 16777216)   Xb  bf16 (M_*D_)
//   [16777216 .. 19922944)   Wqb|Wkb|Wvb bf16 (D_*D_ each)
#define WS_QKV   0
#define WS_XB    12582912
#define WS_WB    16777216

// softmax-in-base-2: fold 1/sqrt(DK) * log2(e) into Q
#define QSCALE (0.125f * 1.44269504088896f)

// async global->LDS, 16B per lane; lds base wave-uniform, lane i -> base + i*16
#define GLL16(g, l) __builtin_amdgcn_global_load_lds( \
    (const __attribute__((address_space(1))) void*)(g), \
    (__attribute__((address_space(3))) void*)(l), 16, 0, 0)

#define WAIT_VM0 asm volatile("s_waitcnt vmcnt(0)" ::: "memory")
#define WAIT_VM4 asm volatile("s_waitcnt vmcnt(4)" ::: "memory")
#define WAIT_VM8 asm volatile("s_waitcnt vmcnt(8)" ::: "memory")
#define WAIT_LGKM0 asm volatile("s_waitcnt lgkmcnt(0)" ::: "memory")
#define BARRIER_RAW asm volatile("s_barrier" ::: "memory")

static __device__ __forceinline__ short f2bf(float f){
  union { float f; unsigned u; } x; x.f = f;
  unsigned r = x.u + 0x7fff + ((x.u >> 16) & 1);   // round-to-nearest-even
  return (short)(r >> 16);
}

// ---------------------------------------------------------------------------
// Kernel 0: downcast f32 inputs (X, Wq, Wk, Wv) to bf16 in workspace.
// ---------------------------------------------------------------------------
__global__ __launch_bounds__(256) void cvt_bf16(
    const float* __restrict__ X,  const float* __restrict__ Wq,
    const float* __restrict__ Wk, const float* __restrict__ Wv,
    short* __restrict__ ws)
{
  const int z = blockIdx.z;
  const float* src; short* dst; int n;
  if (z == 0)      { src = X;  dst = ws + WS_XB;               n = M_*D_; }
  else if (z == 1) { src = Wq; dst = ws + WS_WB;               n = D_*D_; }
  else if (z == 2) { src = Wk; dst = ws + WS_WB + D_*D_;       n = D_*D_; }
  else             { src = Wv; dst = ws + WS_WB + 2*(D_*D_);   n = D_*D_; }
  const int stride = gridDim.x * blockDim.x * 4;
  for (int i = (blockIdx.x * blockDim.x + threadIdx.x) * 4; i < n; i += stride) {
    float4 v = *(const float4*)(src + i);
    short4v o;
    o.x = f2bf(v.x); o.y = f2bf(v.y); o.z = f2bf(v.z); o.w = f2bf(v.w);
    *(short4v*)(dst + i) = o;
  }
}

// ---------------------------------------------------------------------------
// Kernel 1: QKV projection, 256x256 tile, BK=32, 8 waves (2Mx4N), 512 thr.
// (unchanged this round — ~49us inferred; will revisit with counters once it
//  is the top dispatch again)
// ---------------------------------------------------------------------------
__global__ __launch_bounds__(512, 2) void qkv_gemm(
    const short* __restrict__ ws_in,
    const float* __restrict__ bq, const float* __restrict__ bk,
    const float* __restrict__ bv, short* __restrict__ qkv)
{
  const int z = blockIdx.z;
  const short* X  = ws_in + WS_XB;
  const short* Wm = ws_in + WS_WB + (size_t)z * (D_*D_);
  short* out = qkv + (size_t)z * (M_*D_);

  __shared__ __align__(16) short lds[65536];

  const int t = threadIdx.x;            // 0..511
  const int w = t >> 6, lane = t & 63;
  const int quad = lane >> 4, l16 = lane & 15;
  const int wm = w >> 2, wn = w & 3;    // wave grid 2(M) x 4(N)
  const int m0 = blockIdx.y * 256, n0 = blockIdx.x * 256;

  const int rl = t >> 2;
  const int sl = (t & 3) ^ (rl & 3);
  const short* sA0 = X  + (size_t)(m0 + rl) * D_ + sl*8;
  const short* sA1 = sA0 + (size_t)128 * D_;
  const short* sB0 = Wm + (size_t)(n0 + rl) * D_ + sl*8;
  const short* sB1 = sB0 + (size_t)128 * D_;
  const int ldsw = w << 9;

  const int swz = quad ^ (l16 & 3);

  f32x4 acc[8][4];
  #pragma unroll
  for (int i=0;i<8;i++)
    #pragma unroll
    for (int j=0;j<4;j++) acc[i][j] = (f32x4){0.f,0.f,0.f,0.f};

  #pragma unroll
  for (int p=0;p<3;p++){
    GLL16(sA0 + p*32, lds + p*16384 + ldsw);
    GLL16(sA1 + p*32, lds + p*16384 + 4096 + ldsw);
    GLL16(sB0 + p*32, lds + p*16384 + 8192 + ldsw);
    GLL16(sB1 + p*32, lds + p*16384 + 12288 + ldsw);
  }
  WAIT_VM8;
  BARRIER_RAW;

  for (int kt = 0; kt < 32; kt++) {
    const int bf = kt & 3;
    const short* bufA = lds + bf*16384;
    const short* bufB = bufA + 8192;
    const int tb = (kt + 3) & 3;
    const int ko2 = (kt + 3) * 32;
    const bool st = (kt + 3) < 32;

    short8 aF[4], bF[4];
    // ---------------- phase A: M-half 0 ----------------
    #pragma unroll
    for (int mf=0; mf<4; mf++)
      aF[mf] = *(const short8*)(bufA + (wm*128 + mf*16 + l16)*32 + swz*8);
    #pragma unroll
    for (int nf=0; nf<4; nf++)
      bF[nf] = *(const short8*)(bufB + (wn*64 + nf*16 + l16)*32 + swz*8);
    if (st) {
      GLL16(sA0 + ko2, lds + tb*16384 + ldsw);
      GLL16(sA1 + ko2, lds + tb*16384 + 4096 + ldsw);
    }
    BARRIER_RAW;
    WAIT_LGKM0;
    __builtin_amdgcn_s_setprio(1);
    #pragma unroll
    for (int mf=0; mf<4; mf++)
      #pragma unroll
      for (int nf=0; nf<4; nf++)
        acc[mf][nf] = __builtin_amdgcn_mfma_f32_16x16x32_bf16(aF[mf], bF[nf], acc[mf][nf], 0,0,0);
    __builtin_amdgcn_s_setprio(0);
    BARRIER_RAW;

    // ---------------- phase B: M-half 1 (B frags reused) ----------------
    #pragma unroll
    for (int mf=0; mf<4; mf++)
      aF[mf] = *(const short8*)(bufA + (wm*128 + 64 + mf*16 + l16)*32 + swz*8);
    if (st) {
      GLL16(sB0 + ko2, lds + tb*16384 + 8192 + ldsw);
      GLL16(sB1 + ko2, lds + tb*16384 + 12288 + ldsw);
    }
    BARRIER_RAW;
    WAIT_LGKM0;
    __builtin_amdgcn_s_setprio(1);
    #pragma unroll
    for (int mf=0; mf<4; mf++)
      #pragma unroll
      for (int nf=0; nf<4; nf++)
        acc[4+mf][nf] = __builtin_amdgcn_mfma_f32_16x16x32_bf16(aF[mf], bF[nf], acc[4+mf][nf], 0,0,0);
    __builtin_amdgcn_s_setprio(0);
    if      (kt < 29)  { WAIT_VM8; }
    else if (kt == 29) { WAIT_VM4; }
    else if (kt == 30) { WAIT_VM0; }
    BARRIER_RAW;
  }

  __syncthreads();

  if (z != 2) {
    const float scale = (z==0) ? QSCALE : 1.0f;
    const float* bias = (z==0) ? bq : bk;
    float bv4[4];
    #pragma unroll
    for (int nf=0; nf<4; nf++) bv4[nf] = bias[n0 + wn*64 + nf*16 + l16];
    short* ep = lds;
    #pragma unroll
    for (int p=0; p<2; p++){
      if (wm == p){
        #pragma unroll
        for (int mf=0; mf<8; mf++)
          #pragma unroll
          for (int nf=0; nf<4; nf++)
            #pragma unroll
            for (int i=0; i<4; i++)
              ep[(mf*16 + quad*4 + i)*264 + wn*64 + nf*16 + l16] =
                  f2bf((acc[mf][nf][i] + bv4[nf]) * scale);
      }
      __syncthreads();
      #pragma unroll
      for (int it=0; it<8; it++){
        const int cid = it*512 + t;
        const int row = cid >> 5, cc = cid & 31;
        short8 vv = *(const short8*)(ep + row*264 + cc*8);
        const int m = m0 + p*128 + row, bidx = m >> 11, s = m & 2047;
        const int n = n0 + cc*8, h = n >> 6, dd = n & 63;
        *(short8*)(out + (((size_t)(bidx*H_ + h))*S_ + s)*DK_ + dd) = vv;
      }
      __syncthreads();
    }
  } else {
    float bv4[4];
    #pragma unroll
    for (int nf=0; nf<4; nf++) bv4[nf] = bv[n0 + wn*64 + nf*16 + l16];
    short* ep = lds;
    #pragma unroll
    for (int p=0; p<2; p++){
      if (wm == p){
        #pragma unroll
        for (int mf=0; mf<8; mf++)
          #pragma unroll
          for (int nf=0; nf<4; nf++)
            #pragma unroll
            for (int i=0; i<4; i++)
              ep[(wn*64 + nf*16 + l16)*136 + mf*16 + quad*4 + i] =
                  f2bf(acc[mf][nf][i] + bv4[nf]);
      }
      __syncthreads();
      #pragma unroll
      for (int it=0; it<8; it++){
        const int cid = it*512 + t;
        const int row = cid >> 4, cc = cid & 15;
        short8 vv = *(const short8*)(ep + row*136 + cc*8);
        const int n = n0 + row, h = n >> 6, dd = n & 63;
        const int m0p = m0 + p*128;
        const int bidx = m0p >> 11;
        const int s = (m0p & 2047) + cc*8;
        *(short8*)(out + (((size_t)(bidx*H_ + h))*DK_ + dd)*S_ + s) = vv;
      }
      __syncthreads();
    }
  }
}

// ---------------------------------------------------------------------------
// Kernel 2: flash-style causal attention — m214-style 8-wave 32x32 structure.
//   - 512 thr (8 waves), each wave owns 32 q-rows -> 256-row q-tile;
//     grid (8, 32) = 256 blocks = exactly 1 block/CU.
//   - KVBLK=64; K,V double-buffered in XOR-swizzled LDS (32 KB total).
//   - mfma_f32_32x32x16_bf16 (2x FLOP per LDS byte vs 16x16x32).
//   - S^T = K @ Q^T so each lane's P row is lane-local in q; P converted to
//     bf16 A-fragments IN REGISTERS via v_cvt_pk_bf16_f32 + permlane32_swap
//     (T12): no Ps LDS buffer, no same-wave LDS RAW drain.
//   - base-2 softmax, no running max (QSCALE folded into Q).
// Lane algebra (verified):
//   S^T C-layout: key = (r&3)+8*(r>>2)+4h, q = l32  (h = lane>>5)
//   PV A-layout:  row(q) = l32, k(key) = 8h+j
//   chunk kk (16 keys): target dword d needs c[e=h_t][m=d&1] from half d>>1,
//   where c[e][m] = cvt_pk(s[8u+4e+2m], s[8u+4e+2m+1]); one permlane32_swap
//   per (X_m=c[0][m], Y_m=c[1][m]) pair delivers dwords {m} and {2+m}.
// ---------------------------------------------------------------------------
__global__ __launch_bounds__(512, 2) void attn(
    const short* __restrict__ qkv, float* __restrict__ out)
{
  const int bh = blockIdx.y;               // b*16 + h, 0..31
  const int qt = 7 - blockIdx.x;           // 256-row q-tile, longest first
  const short* Q  = qkv + (size_t)bh * (S_*DK_);
  const short* K  = Q + (size_t)(M_*D_);
  const short* VT = qkv + (size_t)(2*M_*D_) + (size_t)bh * (DK_*S_);  // [d][s]

  __shared__ short Kbuf[2][4096];   // [64 key][64 d] swizzled, 8KB each
  __shared__ short Vbuf[2][4096];   // [64 d][64 key] swizzled, 8KB each

  const int t = threadIdx.x;
  const int w = t >> 6, lane = t & 63;
  const int l32 = lane & 31, h = lane >> 5;

  const int q0w = qt*256 + w*32;           // wave's first q row

  // Q B-frags: lane holds B[k=8h+j][col=l32] = Q[q0w+l32][dc*16+8h+j]
  short8 bq[4];
  #pragma unroll
  for (int dc=0; dc<4; dc++)
    bq[dc] = *(const short8*)(Q + (size_t)(q0w + l32)*DK_ + dc*16 + h*8);

  // staging: wave w covers tile rows w*8..w*8+7; lane -> row w*8+(lane>>3),
  // phys chunk lane&7; source logical chunk = (lane&7)^(lane>>3).
  const int sr  = w*8 + (lane >> 3);
  const int sc8 = ((lane & 7) ^ (lane >> 3)) * 8;

  const int nkt = 4*(qt+1);
  // prime: tile 0 into buffer 0 (2 vmem ops/wave)
  GLL16(K  + (size_t)sr*DK_ + sc8, &Kbuf[0][0] + w*512);
  GLL16(VT + (size_t)sr*S_  + sc8, &Vbuf[0][0] + w*512);

  f32x16 o0 = {0.f,0.f,0.f,0.f,0.f,0.f,0.f,0.f,0.f,0.f,0.f,0.f,0.f,0.f,0.f,0.f};
  f32x16 o1 = o0;
  float lsum = 0.f;
  const int xrow = l32 & 7;               // read-side row-XOR component

  for (int kt = 0; kt < nkt; kt++){
    const int cur = kt & 1;
    WAIT_VM0;          // tile kt (and, at kt==0, the Q loads) complete
    BARRIER_RAW;
    if (kt + 1 < nkt) {
      const int kb2 = (kt+1)*64;
      GLL16(K  + (size_t)(kb2 + sr)*DK_ + sc8, &Kbuf[cur^1][0] + w*512);
      GLL16(VT + (size_t)sr*S_ + kb2 + sc8,    &Vbuf[cur^1][0] + w*512);
    }
    const int kb = kt*64;
    if (kb > q0w + 31) continue;          // wave fully masked; keep barriers

    const short* Kc = &Kbuf[cur][0];
    const short* Vc = &Vbuf[cur][0];

    // ---- S^T = K @ Q^T : 8 MFMA, 8 ds_read_b128 ----
    f32x16 s[2];
    s[0] = o0 - o0;  // cheap zero16
    s[1] = s[0];
    #pragma unroll
    for (int dc=0; dc<4; dc++){
      const int xk = ((dc*2 + h) ^ xrow)*8;
      short8 a0 = *(const short8*)(Kc + l32*64 + xk);
      short8 a1 = *(const short8*)(Kc + (32 + l32)*64 + xk);
      s[0] = __builtin_amdgcn_mfma_f32_32x32x16_bf16(a0, bq[dc], s[0], 0,0,0);
      s[1] = __builtin_amdgcn_mfma_f32_32x32x16_bf16(a1, bq[dc], s[1], 0,0,0);
    }

    // ---- causal mask (tiles straddling the diagonal only) ----
    if (kb + 63 > q0w) {
      const int qg = q0w + l32;
      #pragma unroll
      for (int r=0; r<16; r++){
        const int k0 = kb + (r&3) + 8*(r>>2) + 4*h;
        if (k0      > qg) s[0][r] = -3.0e38f;
        if (k0 + 32 > qg) s[1][r] = -3.0e38f;
      }
    }

    // ---- p = exp2(s); in-register pack to PV A-fragments (T12) ----
    short8 pf[4];
    #pragma unroll
    for (int mk=0; mk<2; mk++){
      #pragma unroll
      for (int u=0; u<2; u++){
        float p0 = __builtin_amdgcn_exp2f(s[mk][8*u+0]);
        float p1 = __builtin_amdgcn_exp2f(s[mk][8*u+1]);
        float p2 = __builtin_amdgcn_exp2f(s[mk][8*u+2]);
        float p3 = __builtin_amdgcn_exp2f(s[mk][8*u+3]);
        float p4 = __builtin_amdgcn_exp2f(s[mk][8*u+4]);
        float p5 = __builtin_amdgcn_exp2f(s[mk][8*u+5]);
        float p6 = __builtin_amdgcn_exp2f(s[mk][8*u+6]);
        float p7 = __builtin_amdgcn_exp2f(s[mk][8*u+7]);
        lsum += ((p0+p1)+(p2+p3)) + ((p4+p5)+(p6+p7));
        unsigned X0, X1, Y0, Y1;
        asm("v_cvt_pk_bf16_f32 %0, %1, %2" : "=v"(X0) : "v"(p0), "v"(p1));
        asm("v_cvt_pk_bf16_f32 %0, %1, %2" : "=v"(X1) : "v"(p2), "v"(p3));
        asm("v_cvt_pk_bf16_f32 %0, %1, %2" : "=v"(Y0) : "v"(p4), "v"(p5));
        asm("v_cvt_pk_bf16_f32 %0, %1, %2" : "=v"(Y1) : "v"(p6), "v"(p7));
        asm("v_permlane32_swap_b32 %0, %1" : "+v"(X0), "+v"(Y0));
        asm("v_permlane32_swap_b32 %0, %1" : "+v"(X1), "+v"(Y1));
        union { unsigned u4[4]; short8 s8; } pp;
        pp.u4[0] = X0; pp.u4[1] = X1; pp.u4[2] = Y0; pp.u4[3] = Y1;
        pf[mk*2 + u] = pp.s8;
      }
    }

    // ---- PV: o += P @ V : 8 MFMA, 8 ds_read_b128 ----
    #pragma unroll
    for (int kk=0; kk<4; kk++){
      const int xv = ((kk*2 + h) ^ xrow)*8;
      short8 v0 = *(const short8*)(Vc + l32*64 + xv);
      short8 v1 = *(const short8*)(Vc + (32 + l32)*64 + xv);
      o0 = __builtin_amdgcn_mfma_f32_32x32x16_bf16(pf[kk], v0, o0, 0,0,0);
      o1 = __builtin_amdgcn_mfma_f32_32x32x16_bf16(pf[kk], v1, o1, 0,0,0);
    }
  }

  // ---- epilogue: row sums across halves, normalize, store f32 ----
  float rs = lsum + __shfl_xor(lsum, 32, 64);
  float linv = 1.0f / rs;                  // valid for q = l32 (both halves)
  const int bb = bh >> 4, hh = bh & 15;
  #pragma unroll
  for (int r=0; r<16; r++){
    const int qrow = (r&3) + 8*(r>>2) + 4*h;
    const float lw = __shfl(linv, qrow, 64);
    const int qg = q0w + qrow;
    float* dst = out + ((size_t)bb*S_ + qg)*D_ + hh*DK_;
    dst[l32]      = o0[r] * lw;
    dst[32 + l32] = o1[r] * lw;
  }
}

extern "C" void kernel_launch(void* const* d_in, const int* in_sizes, int n_in,
                              void* d_out, int out_size, void* d_ws, size_t ws_size,
                              hipStream_t stream)
{
  (void)in_sizes; (void)n_in; (void)out_size; (void)ws_size;
  const float* X  = (const float*)d_in[0];
  const float* Wq = (const float*)d_in[1];
  const float* bq = (const float*)d_in[2];
  const float* Wk = (const float*)d_in[3];
  const float* bk = (const float*)d_in[4];
  const float* Wv = (const float*)d_in[5];
  const float* bv = (const float*)d_in[6];
  short* ws  = (short*)d_ws;
  float* out = (float*)d_out;

  dim3 g0(1024, 1, 4);
  cvt_bf16<<<g0, dim3(256,1,1), 0, stream>>>(X, Wq, Wk, Wv, ws);
  dim3 g1(D_/256, M_/256, 3);       // 4 x 16 x 3 = 192 blocks, 512 thr
  qkv_gemm<<<g1, dim3(512,1,1), 0, stream>>>(ws, bq, bk, bv, ws + WS_QKV);
  dim3 g2(8, B_*H_);                // 8 x 32 = 256 blocks, 512 thr
  attn<<<g2, dim3(512,1,1), 0, stream>>>(ws + WS_QKV, out);
}